// Round 25
// baseline (188.618 us; speedup 1.0000x reference)
//
#include <hip/hip_runtime.h>

#define C_LENX 2048
#define Q_LENX 512
#define BATCH  32
#define HDIM   256
#define BH     8192
#define CBLK   64             // 4 waves x 16 c-rows (single set)
#define QBLK   32
#define NQT    16
#define TILE_BYTES 32768      // blob tile: qf 16K (LDS image) + qt 16K (global-read, pi-order)
#define OFF_QT 16384
#define QF_BYTES 16384

typedef __attribute__((ext_vector_type(8))) _Float16 f16x8;
typedef __attribute__((ext_vector_type(4))) float f32x4;

__device__ __forceinline__ unsigned short f2h_bits(float x) {
    union { _Float16 h; unsigned short u; } cv;
    cv.h = (_Float16)x;                     // RTNE
    return cv.u;
}

// async global->LDS, 16B per lane, wave-uniform LDS base + lane*16
__device__ __forceinline__ void stage16(const void* gsrc, void* ldst) {
    __builtin_amdgcn_global_load_lds(
        (const __attribute__((address_space(1))) unsigned int*)gsrc,
        (__attribute__((address_space(3))) unsigned int*)ldst, 16, 0, 0);
}

// ---------------- prep: fp32 Q -> fp16 blob (identical to R21/R24) ----------------
// qf: row q (512B); 16B chunk c at byte q*512 + 16*(c ^ (q&7))     [holds Q[q][8c..8c+7]]
// qt: chunk (h*4+g), PI-PERMUTED q-octet: { Q[4g..4g+3][h], Q[16+4g..16+4g+3][h] }
//     — matches the in-register P layout of lane group g, so PV needs no P shuffle.
__global__ __launch_bounds__(256)
void q_prep(const float* __restrict__ question, unsigned char* __restrict__ blob)
{
    __shared__ unsigned short sHf[QBLK][264];
    const int tid = threadIdx.x;
    const int b  = blockIdx.x >> 4;
    const int t  = blockIdx.x & 15;
    const float* qbase = question + (size_t)(t * QBLK) * BH + b * HDIM;
    unsigned char* tb = blob + (size_t)(b * NQT + t) * TILE_BYTES;

    #pragma unroll
    for (int i = 0; i < 8; ++i) {
        int e  = tid + i * 256;          // float4 cell 0..2047
        int qr = e >> 6;                 // 0..31
        int h4 = (e & 63) << 2;          // 0..252
        float4 x = *reinterpret_cast<const float4*>(qbase + (size_t)qr * BH + h4);
        ushort4 hv;
        hv.x = f2h_bits(x.x); hv.y = f2h_bits(x.y);
        hv.z = f2h_bits(x.z); hv.w = f2h_bits(x.w);
        *reinterpret_cast<ushort4*>(&sHf[qr][h4]) = hv;
        int c = h4 >> 3;                 // 16B chunk within row
        *reinterpret_cast<ushort4*>(tb + qr * 512 + ((c ^ (qr & 7)) << 4) + ((h4 & 7) << 1)) = hv;
    }
    __syncthreads();
    #pragma unroll
    for (int i = 0; i < 4; ++i) {
        int e  = tid + i * 256;          // chunk 0..1023
        int h  = e >> 2;                 // 0..255
        int g  = e & 3;                  // lane-group
        int q0 = g * 4;
        ushort4 a, bv;
        a.x  = sHf[q0 + 0][h];      a.y  = sHf[q0 + 1][h];
        a.z  = sHf[q0 + 2][h];      a.w  = sHf[q0 + 3][h];
        bv.x = sHf[16 + q0 + 0][h]; bv.y = sHf[16 + q0 + 1][h];
        bv.z = sHf[16 + q0 + 2][h]; bv.w = sHf[16 + q0 + 3][h];
        *reinterpret_cast<ushort4*>(tb + OFF_QT + e * 16)     = a;
        *reinterpret_cast<ushort4*>(tb + OFF_QT + e * 16 + 8) = bv;
    }
}

// ---- main: SINGLE c-set, qf-only 32KB LDS dbuf, qt from L2 in-loop, 3 waves/SIMD ----
__global__ __launch_bounds__(256, 3)
void s2s_attn(const float* __restrict__ content,
              const unsigned char* __restrict__ blob,
              const int*   __restrict__ qmask,
              float*       __restrict__ out)
{
    __shared__ __attribute__((aligned(16))) unsigned char sBuf[2 * QF_BYTES];

    const int tid  = threadIdx.x;
    const int wid  = tid >> 6;
    const int lane = tid & 63;
    const int lr   = lane & 15;
    const int lg   = lane >> 4;

    // XCD-aware swizzle: 1024 blocks, 128/XCD -> each XCD owns 4 complete batches
    const int lin = (blockIdx.x & 7) * 128 + (blockIdx.x >> 3);
    const int ct = lin & 31;             // 32 c-tiles per batch
    const int b  = lin >> 5;
    const int c0 = ct * CBLK;

    // prologue: DMA qf(0) into buffer 0 (16 segs of 1KB; 4 per wave)
    {
        const unsigned char* tb0 = blob + (size_t)(b * NQT) * TILE_BYTES;
        #pragma unroll
        for (int j = 0; j < 4; ++j) {
            int seg = wid * 4 + j;
            stage16(tb0 + seg * 1024 + lane * 16, sBuf + seg * 1024);
        }
    }

    // content preload: 16 c-rows (K=32 A/B layout: row=lr, k=lg*8)
    f16x8 chi[8];
    {
        const float* cb0 = content + (size_t)(c0 + wid*16 + lr) * BH + b*HDIM + lg*8;
        #pragma unroll
        for (int kc = 0; kc < 8; ++kc) {
            float4 x0 = *reinterpret_cast<const float4*>(cb0 + kc*32);
            float4 x1 = *reinterpret_cast<const float4*>(cb0 + kc*32 + 4);
            float xs[8] = {x0.x,x0.y,x0.z,x0.w,x1.x,x1.y,x1.z,x1.w};
            #pragma unroll
            for (int j = 0; j < 8; ++j)
                chi[kc][j] = (_Float16)xs[j];
        }
    }

    // acc[n]: O^T fragment — lane holds O[c = c0 + wid*16 + lr][h = n*16 + lg*4 + r]
    f32x4 acc[16];
    #pragma unroll
    for (int n = 0; n < 16; ++n) { f32x4 z = {0.f,0.f,0.f,0.f}; acc[n] = z; }
    float m_run = -INFINITY;
    float l_run = 0.f;                  // per-lane PARTIAL sum; reduced at epilogue

    const int mrow = b * Q_LENX + (lane & 31);
    int mval = qmask[mrow];             // tile-0 mask value (prefetched)

    __syncthreads();           // qf(0) DMA drained + visible

    for (int t = 0; t < NQT; ++t) {
        const unsigned char* qf = sBuf + (t & 1) * QF_BYTES;
        const unsigned char* gqt = blob + (size_t)(b * NQT + t) * TILE_BYTES + OFF_QT;

        // T3 2-phase: issue next tile's qf DMA into the other buffer
        if (t + 1 < NQT) {
            const unsigned char* tbn = blob + (size_t)(b * NQT + t + 1) * TILE_BYTES;
            unsigned char* db = sBuf + ((t + 1) & 1) * QF_BYTES;
            #pragma unroll
            for (int j = 0; j < 4; ++j) {
                int seg = wid * 4 + j;
                stage16(tbn + seg * 1024 + lane * 16, db + seg * 1024);
            }
        }
        const unsigned mw = (unsigned)__ballot(mval != 0);
        if (t + 1 < NQT) mval = qmask[mrow + (t + 1) * QBLK];

        // ---- swapped QK^T: S^T = mfma(A=Q, B=C); 2 chains, depth 8, from qf LDS ----
        f32x4 zz = {0.f,0.f,0.f,0.f};
        f32x4 sA0 = zz, sB0 = zz;
        const unsigned swz = (unsigned)(lr & 7);   // (16+lr)&7 == lr&7
        #pragma unroll
        for (int kc = 0; kc < 8; ++kc) {
            unsigned off = (unsigned)((kc*4 + lg) ^ swz) << 4;
            f16x8 qa = *reinterpret_cast<const f16x8*>(qf + lr*512 + off);
            f16x8 qb = *reinterpret_cast<const f16x8*>(qf + (16+lr)*512 + off);
            sA0 = __builtin_amdgcn_mfma_f32_16x16x32_f16(qa, chi[kc], sA0, 0, 0, 0);
            sB0 = __builtin_amdgcn_mfma_f32_16x16x32_f16(qb, chi[kc], sB0, 0, 0, 0);
        }
        // sA0: S^T rows q=lg*4+r, col c=lr;  sB0: rows q=16+lg*4+r

        // ---- masked score collection; uniform-mask fast path (mw is SGPR) ----
        float p0v[8];
        float tm0 = -INFINITY;          // LANE-LOCAL max
        if (mw == 0xffffffffu) {
            #pragma unroll
            for (int r = 0; r < 4; ++r) {
                p0v[r] = sA0[r]; p0v[4+r] = sB0[r];
                tm0 = fmaxf(tm0, fmaxf(sA0[r], sB0[r]));
            }
        } else {
            #pragma unroll
            for (int r = 0; r < 4; ++r) {
                bool okA = (mw >> (lg*4 + r)) & 1u;
                bool okB = (mw >> (16 + lg*4 + r)) & 1u;
                float a0 = okA ? sA0[r] : -INFINITY;
                float b0v = okB ? sB0[r] : -INFINITY;
                p0v[r] = a0; p0v[4+r] = b0v;
                tm0 = fmaxf(tm0, fmaxf(a0, b0v));
            }
        }

        // ---- T13 defer-max, LAZY reduce: cross-lane true-max only on update tiles ----
        if (__ballot(tm0 > m_run + 4.0f)) {
            tm0 = fmaxf(tm0, __shfl_xor(tm0, 16, 64));
            tm0 = fmaxf(tm0, __shfl_xor(tm0, 32, 64));
            float mn0 = fmaxf(m_run, tm0);
            float sc0 = 1.f;
            if (mn0 != -INFINITY) { sc0 = __expf(m_run - mn0); m_run = mn0; }
            l_run *= sc0;
            #pragma unroll
            for (int n = 0; n < 16; ++n)
                acc[n] *= sc0;
        }

        // ---- exp + partial sum; P stays IN REGISTERS (pi-order == B-frag order) ----
        _Float16 ph[8];
        {
            float ps = 0.f;
            if (m_run == -INFINITY) {
                #pragma unroll
                for (int i = 0; i < 8; ++i) ph[i] = (_Float16)0.f;
            } else {
                #pragma unroll
                for (int i = 0; i < 8; ++i) {
                    float e = __expf(p0v[i] - m_run);
                    ph[i] = (_Float16)e;
                    ps += (float)ph[i];            // sum ROUNDED weights (partial)
                }
            }
            l_run += ps;     // cross-lane reduce deferred to epilogue
        }

        // pf: K=32 B-frag under pi-permuted K-axis — pure register pack, no LDS/shuffle.
        f16x8 pf = {ph[0], ph[1], ph[2], ph[3], ph[4], ph[5], ph[6], ph[7]};

        // ---- PV at K=32: vt read IN-LOOP from L2-resident blob (coalesced 1KB/wave/n) ----
        #pragma unroll
        for (int n = 0; n < 16; ++n) {
            f16x8 vt = *reinterpret_cast<const f16x8*>(gqt + (((n*16 + lr)*4 + lg) << 4));
            acc[n] = __builtin_amdgcn_mfma_f32_16x16x32_f16(vt, pf, acc[n], 0, 0, 0);
        }

        __syncthreads();   // all waves done with qf(t); qf(t+1) DMA drained
    }

    // ---- epilogue: reduce partial l across the 4 row-group lanes, then store ----
    l_run += __shfl_xor(l_run, 16, 64);
    l_run += __shfl_xor(l_run, 32, 64);
    float rinv = 1.f / l_run;
    float* orow = out + (size_t)(c0 + wid*16 + lr) * BH + b*HDIM;
    #pragma unroll
    for (int n = 0; n < 16; ++n) {
        f32x4 v = acc[n] * rinv;
        *reinterpret_cast<f32x4*>(orow + n*16 + lg*4) = v;
    }
}

extern "C" void kernel_launch(void* const* d_in, const int* in_sizes, int n_in,
                              void* d_out, int out_size, void* d_ws, size_t ws_size,
                              hipStream_t stream) {
    const float* content  = (const float*)d_in[0];
    const float* question = (const float*)d_in[1];
    const int*   mask     = (const int*)d_in[2];
    float*       out      = (float*)d_out;

    unsigned char* blob = (unsigned char*)d_ws;   // 512 tiles * 32KB = 16 MB

    q_prep<<<BATCH * NQT, 256, 0, stream>>>(question, blob);
    s2s_attn<<<C_LENX / CBLK * BATCH, 256, 0, stream>>>(content, blob, mask, out);
}

// Round 26
// 74.453 us; speedup vs baseline: 2.5334x; 2.5334x over previous
//
#include <hip/hip_runtime.h>

#define C_LENX 2048
#define Q_LENX 512
#define BATCH  32
#define HDIM   256
#define BH     8192
#define CBLK   128            // 2 c-sets x 4 waves x 16 rows
#define QBLK   32
#define NQT    16
#define TILE_BYTES 32768      // qf 16K (fp16[32][256], swz) + qt 16K (V^T chunks, pi-order)
#define OFF_QT 16384

typedef __attribute__((ext_vector_type(8))) _Float16 f16x8;
typedef __attribute__((ext_vector_type(4))) float f32x4;

__device__ __forceinline__ unsigned short f2h_bits(float x) {
    union { _Float16 h; unsigned short u; } cv;
    cv.h = (_Float16)x;                     // RTNE
    return cv.u;
}

// async global->LDS, 16B per lane, wave-uniform LDS base + lane*16
__device__ __forceinline__ void stage16(const void* gsrc, void* ldst) {
    __builtin_amdgcn_global_load_lds(
        (const __attribute__((address_space(1))) unsigned int*)gsrc,
        (__attribute__((address_space(3))) unsigned int*)ldst, 16, 0, 0);
}

// ---------------- prep: fp32 Q -> fp16 blob (identical to R21) ----------------
// qf: row q (512B); 16B chunk c at byte q*512 + 16*(c ^ (q&7))     [holds Q[q][8c..8c+7]]
// qt: chunk (h*4+g), PI-PERMUTED q-octet: { Q[4g..4g+3][h], Q[16+4g..16+4g+3][h] }
__global__ __launch_bounds__(256)
void q_prep(const float* __restrict__ question, unsigned char* __restrict__ blob)
{
    __shared__ unsigned short sHf[QBLK][264];
    const int tid = threadIdx.x;
    const int b  = blockIdx.x >> 4;
    const int t  = blockIdx.x & 15;
    const float* qbase = question + (size_t)(t * QBLK) * BH + b * HDIM;
    unsigned char* tb = blob + (size_t)(b * NQT + t) * TILE_BYTES;

    #pragma unroll
    for (int i = 0; i < 8; ++i) {
        int e  = tid + i * 256;          // float4 cell 0..2047
        int qr = e >> 6;                 // 0..31
        int h4 = (e & 63) << 2;          // 0..252
        float4 x = *reinterpret_cast<const float4*>(qbase + (size_t)qr * BH + h4);
        ushort4 hv;
        hv.x = f2h_bits(x.x); hv.y = f2h_bits(x.y);
        hv.z = f2h_bits(x.z); hv.w = f2h_bits(x.w);
        *reinterpret_cast<ushort4*>(&sHf[qr][h4]) = hv;
        int c = h4 >> 3;                 // 16B chunk within row
        *reinterpret_cast<ushort4*>(tb + qr * 512 + ((c ^ (qr & 7)) << 4) + ((h4 & 7) << 1)) = hv;
    }
    __syncthreads();
    #pragma unroll
    for (int i = 0; i < 4; ++i) {
        int e  = tid + i * 256;          // chunk 0..1023
        int h  = e >> 2;                 // 0..255
        int g  = e & 3;                  // lane-group
        int q0 = g * 4;
        ushort4 a, bv;
        a.x  = sHf[q0 + 0][h];      a.y  = sHf[q0 + 1][h];
        a.z  = sHf[q0 + 2][h];      a.w  = sHf[q0 + 3][h];
        bv.x = sHf[16 + q0 + 0][h]; bv.y = sHf[16 + q0 + 1][h];
        bv.z = sHf[16 + q0 + 2][h]; bv.w = sHf[16 + q0 + 3][h];
        *reinterpret_cast<ushort4*>(tb + OFF_QT + e * 16)     = a;
        *reinterpret_cast<ushort4*>(tb + OFF_QT + e * 16 + 8) = bv;
    }
}

// ---- main: R21 + in-place masking (frees p arrays) + depth-4 8-chain QK^T ----
__global__ __launch_bounds__(256, 2)
void s2s_attn(const float* __restrict__ content,
              const unsigned char* __restrict__ blob,
              const int*   __restrict__ qmask,
              float*       __restrict__ out)
{
    __shared__ __attribute__((aligned(16))) unsigned char sBuf[2 * TILE_BYTES];

    const int tid  = threadIdx.x;
    const int wid  = tid >> 6;
    const int lane = tid & 63;
    const int lr   = lane & 15;
    const int lg   = lane >> 4;

    // XCD-aware swizzle: 512 blocks, 64/XCD -> each XCD owns 4 complete batches
    const int lin = (blockIdx.x & 7) * 64 + (blockIdx.x >> 3);
    const int ct = lin & 15;             // 16 c-tiles per batch
    const int b  = lin >> 4;
    const int c0 = ct * CBLK;

    // prologue: DMA tile 0 into buffer 0 (32 segs of 1KB; 8 per wave)
    {
        const unsigned char* tb0 = blob + (size_t)(b * NQT) * TILE_BYTES;
        #pragma unroll
        for (int j = 0; j < 8; ++j) {
            int seg = wid * 8 + j;
            stage16(tb0 + seg * 1024 + lane * 16, sBuf + seg * 1024);
        }
    }

    // hoist mask: one ballot word per q-tile (wave-uniform -> SGPRs)
    unsigned mwv[NQT];
    #pragma unroll
    for (int t = 0; t < NQT; ++t)
        mwv[t] = (unsigned)__ballot(qmask[b * Q_LENX + t * QBLK + (lane & 31)] != 0);

    // content preload: two c-sets of 16 rows each (K=32 A/B layout: row=lr, k=lg*8)
    f16x8 chi0[8], chi1[8];
    {
        const float* cb0 = content + (size_t)(c0 + wid*16 + lr) * BH + b*HDIM + lg*8;
        const float* cb1 = cb0 + (size_t)64 * BH;
        #pragma unroll
        for (int kc = 0; kc < 8; ++kc) {
            float4 x0 = *reinterpret_cast<const float4*>(cb0 + kc*32);
            float4 x1 = *reinterpret_cast<const float4*>(cb0 + kc*32 + 4);
            float4 y0 = *reinterpret_cast<const float4*>(cb1 + kc*32);
            float4 y1 = *reinterpret_cast<const float4*>(cb1 + kc*32 + 4);
            float xs[8] = {x0.x,x0.y,x0.z,x0.w,x1.x,x1.y,x1.z,x1.w};
            float ys[8] = {y0.x,y0.y,y0.z,y0.w,y1.x,y1.y,y1.z,y1.w};
            #pragma unroll
            for (int j = 0; j < 8; ++j) {
                chi0[kc][j] = (_Float16)xs[j];
                chi1[kc][j] = (_Float16)ys[j];
            }
        }
    }

    // acc[s][n]: O^T fragment — lane holds O[c = c0 + s*64 + wid*16 + lr][h = n*16+lg*4+r]
    f32x4 acc0[16], acc1[16];
    #pragma unroll
    for (int n = 0; n < 16; ++n) {
        f32x4 z = {0.f,0.f,0.f,0.f};
        acc0[n] = z; acc1[n] = z;
    }
    float m_run0 = -INFINITY, m_run1 = -INFINITY;
    float l_run0 = 0.f, l_run1 = 0.f;   // per-lane PARTIAL sums; reduced at epilogue

    __syncthreads();           // tile 0 DMA drained + visible

    for (int t = 0; t < NQT; ++t) {
        const unsigned char* qf = sBuf + (t & 1) * TILE_BYTES;
        const unsigned char* qt = qf + OFF_QT;

        // T3 2-phase: issue next tile's DMA into the other buffer, compute, one barrier
        if (t + 1 < NQT) {
            const unsigned char* tbn = blob + (size_t)(b * NQT + t + 1) * TILE_BYTES;
            unsigned char* db = sBuf + ((t + 1) & 1) * TILE_BYTES;
            #pragma unroll
            for (int j = 0; j < 8; ++j) {
                int seg = wid * 8 + j;
                stage16(tbn + seg * 1024 + lane * 16, db + seg * 1024);
            }
        }
        const unsigned mw = mwv[t];

        // ---- QK^T both sets: 8 independent chains (depth 4), shared qf reads ----
        f32x4 zz = {0.f,0.f,0.f,0.f};
        f32x4 sA0a=zz, sB0a=zz, sA1a=zz, sB1a=zz;
        f32x4 sA0b=zz, sB0b=zz, sA1b=zz, sB1b=zz;
        const unsigned swz = (unsigned)(lr & 7);   // (16+lr)&7 == lr&7
        __builtin_amdgcn_s_setprio(1);
        #pragma unroll
        for (int kc = 0; kc < 4; ++kc) {
            unsigned offA = (unsigned)((kc*4 + lg) ^ swz) << 4;
            unsigned offB = (unsigned)(((kc+4)*4 + lg) ^ swz) << 4;
            f16x8 qaA = *reinterpret_cast<const f16x8*>(qf + lr*512 + offA);
            f16x8 qbA = *reinterpret_cast<const f16x8*>(qf + (16+lr)*512 + offA);
            f16x8 qaB = *reinterpret_cast<const f16x8*>(qf + lr*512 + offB);
            f16x8 qbB = *reinterpret_cast<const f16x8*>(qf + (16+lr)*512 + offB);
            sA0a = __builtin_amdgcn_mfma_f32_16x16x32_f16(qaA, chi0[kc],   sA0a, 0, 0, 0);
            sB0a = __builtin_amdgcn_mfma_f32_16x16x32_f16(qbA, chi0[kc],   sB0a, 0, 0, 0);
            sA1a = __builtin_amdgcn_mfma_f32_16x16x32_f16(qaA, chi1[kc],   sA1a, 0, 0, 0);
            sB1a = __builtin_amdgcn_mfma_f32_16x16x32_f16(qbA, chi1[kc],   sB1a, 0, 0, 0);
            sA0b = __builtin_amdgcn_mfma_f32_16x16x32_f16(qaB, chi0[kc+4], sA0b, 0, 0, 0);
            sB0b = __builtin_amdgcn_mfma_f32_16x16x32_f16(qbB, chi0[kc+4], sB0b, 0, 0, 0);
            sA1b = __builtin_amdgcn_mfma_f32_16x16x32_f16(qaB, chi1[kc+4], sA1b, 0, 0, 0);
            sB1b = __builtin_amdgcn_mfma_f32_16x16x32_f16(qbB, chi1[kc+4], sB1b, 0, 0, 0);
        }
        __builtin_amdgcn_s_setprio(0);
        f32x4 sA0 = sA0a + sA0b;   // S^T rows q=lg*4+r,    col c=lr  (set 0)
        f32x4 sB0 = sB0a + sB0b;   // S^T rows q=16+lg*4+r, col c=lr  (set 0)
        f32x4 sA1 = sA1a + sA1b;   // set 1
        f32x4 sB1 = sB1a + sB1b;

        // ---- in-place masking (no p arrays); fast path skips entirely (mw is SGPR) ----
        if (mw != 0xffffffffu) {
            #pragma unroll
            for (int r = 0; r < 4; ++r) {
                bool okA = (mw >> (lg*4 + r)) & 1u;
                bool okB = (mw >> (16 + lg*4 + r)) & 1u;
                sA0[r] = okA ? sA0[r] : -INFINITY;
                sB0[r] = okB ? sB0[r] : -INFINITY;
                sA1[r] = okA ? sA1[r] : -INFINITY;
                sB1[r] = okB ? sB1[r] : -INFINITY;
            }
        }
        float tm0 = -INFINITY, tm1 = -INFINITY;   // LANE-LOCAL maxima
        #pragma unroll
        for (int r = 0; r < 4; ++r) {
            tm0 = fmaxf(tm0, fmaxf(sA0[r], sB0[r]));
            tm1 = fmaxf(tm1, fmaxf(sA1[r], sB1[r]));
        }

        // ---- T13 defer-max, LAZY reduce: cross-lane true-max only on update tiles ----
        if (__ballot((tm0 > m_run0 + 4.0f) || (tm1 > m_run1 + 4.0f))) {
            tm0 = fmaxf(tm0, __shfl_xor(tm0, 16, 64));
            tm0 = fmaxf(tm0, __shfl_xor(tm0, 32, 64));
            tm1 = fmaxf(tm1, __shfl_xor(tm1, 16, 64));
            tm1 = fmaxf(tm1, __shfl_xor(tm1, 32, 64));
            float mn0 = fmaxf(m_run0, tm0);
            float mn1 = fmaxf(m_run1, tm1);
            float sc0 = 1.f, sc1 = 1.f;
            if (mn0 != -INFINITY) { sc0 = __expf(m_run0 - mn0); m_run0 = mn0; }
            if (mn1 != -INFINITY) { sc1 = __expf(m_run1 - mn1); m_run1 = mn1; }
            l_run0 *= sc0; l_run1 *= sc1;
            #pragma unroll
            for (int n = 0; n < 16; ++n) {
                acc0[n] *= sc0;
                acc1[n] *= sc1;
            }
        }

        // ---- exp + partial sums straight from sacc; P stays IN REGISTERS (pi-order) ----
        _Float16 ph0[8], ph1[8];
        {
            float ps0 = 0.f, ps1 = 0.f;
            if (m_run0 == -INFINITY) {
                #pragma unroll
                for (int i = 0; i < 8; ++i) ph0[i] = (_Float16)0.f;
            } else {
                #pragma unroll
                for (int r = 0; r < 4; ++r) {
                    float e0 = __expf(sA0[r] - m_run0);    // exp(-inf)=0 on masked
                    float e1 = __expf(sB0[r] - m_run0);
                    ph0[r]     = (_Float16)e0;
                    ph0[4 + r] = (_Float16)e1;
                    ps0 += (float)ph0[r] + (float)ph0[4 + r];  // sum ROUNDED weights
                }
            }
            if (m_run1 == -INFINITY) {
                #pragma unroll
                for (int i = 0; i < 8; ++i) ph1[i] = (_Float16)0.f;
            } else {
                #pragma unroll
                for (int r = 0; r < 4; ++r) {
                    float e0 = __expf(sA1[r] - m_run1);
                    float e1 = __expf(sB1[r] - m_run1);
                    ph1[r]     = (_Float16)e0;
                    ph1[4 + r] = (_Float16)e1;
                    ps1 += (float)ph1[r] + (float)ph1[4 + r];
                }
            }
            l_run0 += ps0;   // per-lane partial; cross-lane reduce deferred to epilogue
            l_run1 += ps1;
        }

        // pf: K=32 B-frag under pi-permuted K-axis — pure register pack, no LDS/shuffle.
        f16x8 pf0 = {ph0[0], ph0[1], ph0[2], ph0[3], ph0[4], ph0[5], ph0[6], ph0[7]};
        f16x8 pf1 = {ph1[0], ph1[1], ph1[2], ph1[3], ph1[4], ph1[5], ph1[6], ph1[7]};

        // ---- PV both sets at K=32: vt read IN-LOOP (transient reg, proven pressure) ----
        __builtin_amdgcn_s_setprio(1);
        #pragma unroll
        for (int n = 0; n < 16; ++n) {
            f16x8 vt = *reinterpret_cast<const f16x8*>(qt + (((n*16 + lr)*4 + lg) << 4));
            acc0[n] = __builtin_amdgcn_mfma_f32_16x16x32_f16(vt, pf0, acc0[n], 0, 0, 0);
            acc1[n] = __builtin_amdgcn_mfma_f32_16x16x32_f16(vt, pf1, acc1[n], 0, 0, 0);
        }
        __builtin_amdgcn_s_setprio(0);

        __syncthreads();   // all waves done with tile t; next tile's DMA drained
    }

    // ---- epilogue: reduce partial l across the 4 row-group lanes, then store ----
    l_run0 += __shfl_xor(l_run0, 16, 64);
    l_run0 += __shfl_xor(l_run0, 32, 64);
    l_run1 += __shfl_xor(l_run1, 16, 64);
    l_run1 += __shfl_xor(l_run1, 32, 64);
    float rinv0 = 1.f / l_run0;
    float rinv1 = 1.f / l_run1;
    float* orow0 = out + (size_t)(c0 + wid*16 + lr) * BH + b*HDIM;
    float* orow1 = orow0 + (size_t)64 * BH;
    #pragma unroll
    for (int n = 0; n < 16; ++n) {
        f32x4 v0 = acc0[n] * rinv0;
        f32x4 v1 = acc1[n] * rinv1;
        *reinterpret_cast<f32x4*>(orow0 + n*16 + lg*4) = v0;
        *reinterpret_cast<f32x4*>(orow1 + n*16 + lg*4) = v1;
    }
}

extern "C" void kernel_launch(void* const* d_in, const int* in_sizes, int n_in,
                              void* d_out, int out_size, void* d_ws, size_t ws_size,
                              hipStream_t stream) {
    const float* content  = (const float*)d_in[0];
    const float* question = (const float*)d_in[1];
    const int*   mask     = (const int*)d_in[2];
    float*       out      = (float*)d_out;

    unsigned char* blob = (unsigned char*)d_ws;   // 512 tiles * 32KB = 16 MB

    q_prep<<<BATCH * NQT, 256, 0, stream>>>(question, blob);
    s2s_attn<<<C_LENX / CBLK * BATCH, 256, 0, stream>>>(content, blob, mask, out);
}

// Round 27
// 72.501 us; speedup vs baseline: 2.6016x; 1.0269x over previous
//
#include <hip/hip_runtime.h>

#define C_LENX 2048
#define Q_LENX 512
#define BATCH  32
#define HDIM   256
#define BH     8192
#define CBLK   128            // 2 c-sets x 4 waves x 16 rows
#define QBLK   32
#define NQT    16
#define TILE_BYTES 32768      // qf 16K (fp16[32][256], swz) + qt 16K (V^T chunks, pi-order)
#define OFF_QT 16384

typedef __attribute__((ext_vector_type(8))) _Float16 f16x8;
typedef __attribute__((ext_vector_type(4))) float f32x4;

__device__ __forceinline__ unsigned short f2h_bits(float x) {
    union { _Float16 h; unsigned short u; } cv;
    cv.h = (_Float16)x;                     // RTNE
    return cv.u;
}

// async global->LDS, 16B per lane, wave-uniform LDS base + lane*16
__device__ __forceinline__ void stage16(const void* gsrc, void* ldst) {
    __builtin_amdgcn_global_load_lds(
        (const __attribute__((address_space(1))) unsigned int*)gsrc,
        (__attribute__((address_space(3))) unsigned int*)ldst, 16, 0, 0);
}

// ---------------- prep: fp32 Q -> fp16 blob ----------------
// qf: row q (512B); 16B chunk c at byte q*512 + 16*(c ^ (q&7))     [holds Q[q][8c..8c+7]]
// qt: chunk (h*4+g), PI-PERMUTED q-octet: { Q[4g..4g+3][h], Q[16+4g..16+4g+3][h] }
//     — matches the in-register P layout of lane group g, so PV needs no P shuffle.
__global__ __launch_bounds__(256)
void q_prep(const float* __restrict__ question, unsigned char* __restrict__ blob)
{
    __shared__ unsigned short sHf[QBLK][264];
    const int tid = threadIdx.x;
    const int b  = blockIdx.x >> 4;
    const int t  = blockIdx.x & 15;
    const float* qbase = question + (size_t)(t * QBLK) * BH + b * HDIM;
    unsigned char* tb = blob + (size_t)(b * NQT + t) * TILE_BYTES;

    #pragma unroll
    for (int i = 0; i < 8; ++i) {
        int e  = tid + i * 256;          // float4 cell 0..2047
        int qr = e >> 6;                 // 0..31
        int h4 = (e & 63) << 2;          // 0..252
        float4 x = *reinterpret_cast<const float4*>(qbase + (size_t)qr * BH + h4);
        ushort4 hv;
        hv.x = f2h_bits(x.x); hv.y = f2h_bits(x.y);
        hv.z = f2h_bits(x.z); hv.w = f2h_bits(x.w);
        *reinterpret_cast<ushort4*>(&sHf[qr][h4]) = hv;
        int c = h4 >> 3;                 // 16B chunk within row
        *reinterpret_cast<ushort4*>(tb + qr * 512 + ((c ^ (qr & 7)) << 4) + ((h4 & 7) << 1)) = hv;
    }
    __syncthreads();
    #pragma unroll
    for (int i = 0; i < 4; ++i) {
        int e  = tid + i * 256;          // chunk 0..1023
        int h  = e >> 2;                 // 0..255
        int g  = e & 3;                  // lane-group
        int q0 = g * 4;
        ushort4 a, bv;
        a.x  = sHf[q0 + 0][h];      a.y  = sHf[q0 + 1][h];
        a.z  = sHf[q0 + 2][h];      a.w  = sHf[q0 + 3][h];
        bv.x = sHf[16 + q0 + 0][h]; bv.y = sHf[16 + q0 + 1][h];
        bv.z = sHf[16 + q0 + 2][h]; bv.w = sHf[16 + q0 + 3][h];
        *reinterpret_cast<ushort4*>(tb + OFF_QT + e * 16)     = a;
        *reinterpret_cast<ushort4*>(tb + OFF_QT + e * 16 + 8) = bv;
    }
}

// ---- main: R18 structure + register-P (pi-permuted K-axis); vt read in-loop ----
__global__ __launch_bounds__(256, 2)
void s2s_attn(const float* __restrict__ content,
              const unsigned char* __restrict__ blob,
              const int*   __restrict__ qmask,
              float*       __restrict__ out)
{
    __shared__ __attribute__((aligned(16))) unsigned char sBuf[2 * TILE_BYTES];

    const int tid  = threadIdx.x;
    const int wid  = tid >> 6;
    const int lane = tid & 63;
    const int lr   = lane & 15;
    const int lg   = lane >> 4;

    // XCD-aware swizzle: 512 blocks, 64/XCD -> each XCD owns 4 complete batches
    const int lin = (blockIdx.x & 7) * 64 + (blockIdx.x >> 3);
    const int ct = lin & 15;             // 16 c-tiles per batch
    const int b  = lin >> 4;
    const int c0 = ct * CBLK;

    // prologue: DMA tile 0 into buffer 0 (32 segs of 1KB; 8 per wave)
    {
        const unsigned char* tb0 = blob + (size_t)(b * NQT) * TILE_BYTES;
        #pragma unroll
        for (int j = 0; j < 8; ++j) {
            int seg = wid * 8 + j;
            stage16(tb0 + seg * 1024 + lane * 16, sBuf + seg * 1024);
        }
    }

    // hoist mask: one ballot word per q-tile (wave-uniform -> SGPRs)
    unsigned mwv[NQT];
    #pragma unroll
    for (int t = 0; t < NQT; ++t)
        mwv[t] = (unsigned)__ballot(qmask[b * Q_LENX + t * QBLK + (lane & 31)] != 0);

    // content preload: two c-sets of 16 rows each (K=32 A/B layout: row=lr, k=lg*8)
    f16x8 chi0[8], chi1[8];
    {
        const float* cb0 = content + (size_t)(c0 + wid*16 + lr) * BH + b*HDIM + lg*8;
        const float* cb1 = cb0 + (size_t)64 * BH;
        #pragma unroll
        for (int kc = 0; kc < 8; ++kc) {
            float4 x0 = *reinterpret_cast<const float4*>(cb0 + kc*32);
            float4 x1 = *reinterpret_cast<const float4*>(cb0 + kc*32 + 4);
            float4 y0 = *reinterpret_cast<const float4*>(cb1 + kc*32);
            float4 y1 = *reinterpret_cast<const float4*>(cb1 + kc*32 + 4);
            float xs[8] = {x0.x,x0.y,x0.z,x0.w,x1.x,x1.y,x1.z,x1.w};
            float ys[8] = {y0.x,y0.y,y0.z,y0.w,y1.x,y1.y,y1.z,y1.w};
            #pragma unroll
            for (int j = 0; j < 8; ++j) {
                chi0[kc][j] = (_Float16)xs[j];
                chi1[kc][j] = (_Float16)ys[j];
            }
        }
    }

    // acc[s][n]: O^T fragment — lane holds O[c = c0 + s*64 + wid*16 + lr][h = n*16+lg*4+r]
    f32x4 acc0[16], acc1[16];
    #pragma unroll
    for (int n = 0; n < 16; ++n) {
        f32x4 z = {0.f,0.f,0.f,0.f};
        acc0[n] = z; acc1[n] = z;
    }
    float m_run0 = -INFINITY, m_run1 = -INFINITY;
    float l_run0 = 0.f, l_run1 = 0.f;   // per-lane PARTIAL sums; reduced at epilogue

    __syncthreads();           // tile 0 DMA drained + visible

    for (int t = 0; t < NQT; ++t) {
        const unsigned char* qf = sBuf + (t & 1) * TILE_BYTES;
        const unsigned char* qt = qf + OFF_QT;

        // T3 2-phase: issue next tile's DMA into the other buffer, compute, one barrier
        if (t + 1 < NQT) {
            const unsigned char* tbn = blob + (size_t)(b * NQT + t + 1) * TILE_BYTES;
            unsigned char* db = sBuf + ((t + 1) & 1) * TILE_BYTES;
            #pragma unroll
            for (int j = 0; j < 8; ++j) {
                int seg = wid * 8 + j;
                stage16(tbn + seg * 1024 + lane * 16, db + seg * 1024);
            }
        }
        const unsigned mw = mwv[t];

        // ---- QK^T both sets: shared qf reads; 4 chains (2 per set), depth 8 ----
        f32x4 zz = {0.f,0.f,0.f,0.f};
        f32x4 sA0=zz, sB0=zz, sA1=zz, sB1=zz;
        const unsigned swz = (unsigned)(lr & 7);   // (16+lr)&7 == lr&7
        __builtin_amdgcn_s_setprio(1);
        #pragma unroll
        for (int kc = 0; kc < 8; ++kc) {
            unsigned off = (unsigned)((kc*4 + lg) ^ swz) << 4;
            f16x8 qa = *reinterpret_cast<const f16x8*>(qf + lr*512 + off);
            f16x8 qb = *reinterpret_cast<const f16x8*>(qf + (16+lr)*512 + off);
            sA0 = __builtin_amdgcn_mfma_f32_16x16x32_f16(qa, chi0[kc], sA0, 0, 0, 0);
            sB0 = __builtin_amdgcn_mfma_f32_16x16x32_f16(qb, chi0[kc], sB0, 0, 0, 0);
            sA1 = __builtin_amdgcn_mfma_f32_16x16x32_f16(qa, chi1[kc], sA1, 0, 0, 0);
            sB1 = __builtin_amdgcn_mfma_f32_16x16x32_f16(qb, chi1[kc], sB1, 0, 0, 0);
        }
        __builtin_amdgcn_s_setprio(0);
        // sA*: S^T rows q=lg*4+r, col c=lr;  sB*: rows q=16+lg*4+r

        // ---- softmax both sets; uniform-mask fast path (mw is SGPR) ----
        float p0v[8], p1v[8];
        float tm0 = -INFINITY, tm1 = -INFINITY;
        if (mw == 0xffffffffu) {
            #pragma unroll
            for (int r = 0; r < 4; ++r) {
                p0v[r] = sA0[r]; p0v[4+r] = sB0[r];
                p1v[r] = sA1[r]; p1v[4+r] = sB1[r];
                tm0 = fmaxf(tm0, fmaxf(sA0[r], sB0[r]));
                tm1 = fmaxf(tm1, fmaxf(sA1[r], sB1[r]));
            }
        } else {
            #pragma unroll
            for (int r = 0; r < 4; ++r) {
                bool okA = (mw >> (lg*4 + r)) & 1u;
                bool okB = (mw >> (16 + lg*4 + r)) & 1u;
                float a0 = okA ? sA0[r] : -INFINITY;
                float b0v = okB ? sB0[r] : -INFINITY;
                float a1 = okA ? sA1[r] : -INFINITY;
                float b1v = okB ? sB1[r] : -INFINITY;
                p0v[r] = a0; p0v[4+r] = b0v;
                p1v[r] = a1; p1v[4+r] = b1v;
                tm0 = fmaxf(tm0, fmaxf(a0, b0v));
                tm1 = fmaxf(tm1, fmaxf(a1, b1v));
            }
        }
        tm0 = fmaxf(tm0, __shfl_xor(tm0, 16, 64));
        tm0 = fmaxf(tm0, __shfl_xor(tm0, 32, 64));
        tm1 = fmaxf(tm1, __shfl_xor(tm1, 16, 64));
        tm1 = fmaxf(tm1, __shfl_xor(tm1, 32, 64));

        if (__ballot((tm0 > m_run0 + 4.0f) || (tm1 > m_run1 + 4.0f))) {   // T13 defer-max
            float mn0 = fmaxf(m_run0, tm0);
            float mn1 = fmaxf(m_run1, tm1);
            float sc0 = 1.f, sc1 = 1.f;
            if (mn0 != -INFINITY) { sc0 = __expf(m_run0 - mn0); m_run0 = mn0; }
            if (mn1 != -INFINITY) { sc1 = __expf(m_run1 - mn1); m_run1 = mn1; }
            l_run0 *= sc0; l_run1 *= sc1;
            #pragma unroll
            for (int n = 0; n < 16; ++n) {
                acc0[n] *= sc0;
                acc1[n] *= sc1;
            }
        }

        // ---- exp + partial sums; P stays IN REGISTERS (pi-order == B-frag order) ----
        _Float16 ph0[8], ph1[8];
        {
            float ps0 = 0.f, ps1 = 0.f;
            if (m_run0 == -INFINITY) {
                #pragma unroll
                for (int i = 0; i < 8; ++i) ph0[i] = (_Float16)0.f;
            } else {
                #pragma unroll
                for (int i = 0; i < 8; ++i) {
                    float e = __expf(p0v[i] - m_run0);
                    ph0[i] = (_Float16)e;
                    ps0 += (float)ph0[i];          // sum ROUNDED weights (partial)
                }
            }
            if (m_run1 == -INFINITY) {
                #pragma unroll
                for (int i = 0; i < 8; ++i) ph1[i] = (_Float16)0.f;
            } else {
                #pragma unroll
                for (int i = 0; i < 8; ++i) {
                    float e = __expf(p1v[i] - m_run1);
                    ph1[i] = (_Float16)e;
                    ps1 += (float)ph1[i];
                }
            }
            l_run0 += ps0;   // per-lane partial; cross-lane reduce deferred to epilogue
            l_run1 += ps1;
        }

        // pf: K=32 B-frag under pi-permuted K-axis — pure register pack, no LDS/shuffle.
        // B-frag element j = P[pi(lg*8+j)][c=lr]; pi(lg*8+j) = (j<4)? 4lg+j : 16+4lg+j-4,
        // which is exactly ph[j]. qt's q-axis carries the same pi order (q_prep).
        f16x8 pf0 = {ph0[0], ph0[1], ph0[2], ph0[3], ph0[4], ph0[5], ph0[6], ph0[7]};
        f16x8 pf1 = {ph1[0], ph1[1], ph1[2], ph1[3], ph1[4], ph1[5], ph1[6], ph1[7]};

        // ---- PV both sets at K=32: vt read IN-LOOP (transient reg, R18-proven pressure) ----
        __builtin_amdgcn_s_setprio(1);
        #pragma unroll
        for (int n = 0; n < 16; ++n) {
            f16x8 vt = *reinterpret_cast<const f16x8*>(qt + (((n*16 + lr)*4 + lg) << 4));
            acc0[n] = __builtin_amdgcn_mfma_f32_16x16x32_f16(vt, pf0, acc0[n], 0, 0, 0);
            acc1[n] = __builtin_amdgcn_mfma_f32_16x16x32_f16(vt, pf1, acc1[n], 0, 0, 0);
        }
        __builtin_amdgcn_s_setprio(0);

        __syncthreads();   // all waves done with tile t; next tile's DMA drained
    }

    // ---- epilogue: reduce partial l across the 4 row-group lanes, then store ----
    l_run0 += __shfl_xor(l_run0, 16, 64);
    l_run0 += __shfl_xor(l_run0, 32, 64);
    l_run1 += __shfl_xor(l_run1, 16, 64);
    l_run1 += __shfl_xor(l_run1, 32, 64);
    float rinv0 = 1.f / l_run0;
    float rinv1 = 1.f / l_run1;
    float* orow0 = out + (size_t)(c0 + wid*16 + lr) * BH + b*HDIM;
    float* orow1 = orow0 + (size_t)64 * BH;
    #pragma unroll
    for (int n = 0; n < 16; ++n) {
        f32x4 v0 = acc0[n] * rinv0;
        f32x4 v1 = acc1[n] * rinv1;
        *reinterpret_cast<f32x4*>(orow0 + n*16 + lg*4) = v0;
        *reinterpret_cast<f32x4*>(orow1 + n*16 + lg*4) = v1;
    }
}

extern "C" void kernel_launch(void* const* d_in, const int* in_sizes, int n_in,
                              void* d_out, int out_size, void* d_ws, size_t ws_size,
                              hipStream_t stream) {
    const float* content  = (const float*)d_in[0];
    const float* question = (const float*)d_in[1];
    const int*   mask     = (const int*)d_in[2];
    float*       out      = (float*)d_out;

    unsigned char* blob = (unsigned char*)d_ws;   // 512 tiles * 32KB = 16 MB

    q_prep<<<BATCH * NQT, 256, 0, stream>>>(question, blob);
    s2s_attn<<<C_LENX / CBLK * BATCH, 256, 0, stream>>>(content, blob, mask, out);
}